// Round 6
// baseline (26361.511 us; speedup 1.0000x reference)
//
#include <hip/hip_runtime.h>
#include <float.h>

#define V 50000
#define E 100
#define H 512
#define T 200
#define B 256
#define NC 5
#define HB (H * B)

// ---------------- activations (fast, ~2e-7 abs err) ----------------
__device__ __forceinline__ float fsig(float x)  { return 1.f / (1.f + __expf(-x)); }
__device__ __forceinline__ float ftanh(float x) { return 1.f - 2.f / (__expf(2.f * x) + 1.f); }

// ws: h0[2][HB] | h1[2][HB] | hmax[HB] | last[B](int) | cnt(unsigned)
__global__ void k_init(float* __restrict__ ws, const int* __restrict__ X,
                       int* __restrict__ last, unsigned* __restrict__ cnt) {
    int i = blockIdx.x * 256 + threadIdx.x;
    if (i < 4 * HB) ws[i] = 0.f;              // h0 both slots, h1 both slots
    if (i < B) {
        int l = -1;
        const int* xr = X + i * T;
        for (int t = 0; t < T; ++t) if (xr[t] != V) l = t;
        last[i] = l;
    }
    if (i == 0) *cnt = 0u;
}

// stage one 32k x 128b chunk of a [K][B] state matrix
__device__ __forceinline__ void ld_state(float4 (&st)[4], const float* __restrict__ src,
                                         int kb, int r0, int colg) {
#pragma unroll
    for (int p = 0; p < 4; ++p)
        st[p] = *(const float4*)(src + (size_t)(kb + r0 + p * 8) * B + colg);
}
__device__ __forceinline__ void st_state(const float4 (&st)[4], float* __restrict__ buf,
                                         int r0, int col) {
#pragma unroll
    for (int p = 0; p < 4; ++p)
        *(float4*)(buf + (r0 + p * 8) * 128 + col) = st[p];
}

// ---------------- persistent fused LSTM, weights LDS-resident ----------------
// 256 blocks x 256 thr, 1 block/CU (143 KB LDS). Block owns (bt: b-half of 128,
// jg: 4 j's used for BOTH layers). Streams per step:
//  (a) x = h0[t-1], K=512 -> Whh0 (half0 c-set, L0) AND Wih1 (half1 c-set, L1)
//  (b) x = h1[t-2], K=512 -> Whh1, gate-pairs split across halves
//  (c) x = emb(t),  K=112 -> Wih0, gate-pairs split across halves
// c-state and hmax live in registers for the whole 200 steps.
__global__ __launch_bounds__(256, 1) void k_persist(
    const int* __restrict__ X, const float* __restrict__ emb,
    const float* __restrict__ Wih0, const float* __restrict__ Whh0,
    const float* __restrict__ b0,
    const float* __restrict__ Wih1, const float* __restrict__ Whh1,
    const float* __restrict__ b1,
    float* __restrict__ ws, unsigned* __restrict__ cnt)
{
    extern __shared__ float smem[];
    float* wa   = smem;             // [512][32]: c<16 Whh0, c>=16 Wih1 (c = jj*4+g)
    float* wb   = smem + 16384;     // [512][16]: Whh1
    float* wc   = smem + 24576;     // [112][16]: Wih0, zero-padded k>=100
    float* xb   = smem + 26368;     // [2][32][128] staging (dbuf)
    float* redS = smem + 34560;     // [2][128][8] gate-pair exchange

    const int tid  = threadIdx.x;
    const int half = tid >> 7;
    const int tid2 = tid & 127;
    const int jj   = tid2 & 3;
    const int bq   = tid2 >> 2;                 // 0..31
    const int bid  = blockIdx.x;
    const int bt   = (bid >> 2) & 1;            // XCDs 0-3 -> bt0, 4-7 -> bt1
    const int jg   = ((bid >> 3) << 2) | (bid & 3);   // 0..127
    const int b0g  = bt * 128 + bq * 4;
    const int r0   = tid >> 5;
    const int colg = bt * 128 + (tid & 31) * 4;
    const int col  = (tid & 31) * 4;

    float* h0   = ws;
    float* h1   = ws + 2 * HB;
    float* hmax = ws + 4 * HB;
    const int* last = (const int*)(ws + 5 * HB);

    // ---- one-time: weights -> LDS ----
    {
        const int cc = tid & 31, kg = tid >> 5;
        const int rwA = (cc & 3) * H + jg * 4 + ((cc >> 2) & 3);
        const float* sa = (cc < 16) ? (Whh0 + (size_t)rwA * H) : (Wih1 + (size_t)rwA * H);
#pragma unroll
        for (int q = 0; q < 16; ++q) {
            int k = kg * 64 + q * 4;
            float4 v = *(const float4*)(sa + k);
            wa[(k+0)*32+cc] = v.x; wa[(k+1)*32+cc] = v.y;
            wa[(k+2)*32+cc] = v.z; wa[(k+3)*32+cc] = v.w;
        }
        const int c2 = tid & 15, k2 = tid >> 4;
        const int rw2 = (c2 & 3) * H + jg * 4 + (c2 >> 2);
        const float* sb = Whh1 + (size_t)rw2 * H;
#pragma unroll
        for (int q = 0; q < 8; ++q) {
            int k = k2 * 32 + q * 4;
            float4 v = *(const float4*)(sb + k);
            wb[(k+0)*16+c2] = v.x; wb[(k+1)*16+c2] = v.y;
            wb[(k+2)*16+c2] = v.z; wb[(k+3)*16+c2] = v.w;
        }
#pragma unroll
        for (int q = 0; q < 2; ++q) {
            int k = k2 * 8 + q * 4;
            if (k < 112) {
                float4 v = make_float4(0.f, 0.f, 0.f, 0.f);
                if (k < 100) v = *(const float4*)(Wih0 + (size_t)rw2 * E + k);
                wc[(k+0)*16+c2] = v.x; wc[(k+1)*16+c2] = v.y;
                wc[(k+2)*16+c2] = v.z; wc[(k+3)*16+c2] = v.w;
            }
        }
    }
    const int jmine = jg * 4 + jj;
    float bias_r[4];
    {
        const float* bs = half ? b1 : b0;
#pragma unroll
        for (int g = 0; g < 4; ++g) bias_r[g] = bs[g * H + jmine];
    }
    int last4[4] = {0, 0, 0, 0};
    if (half) {
#pragma unroll
        for (int i = 0; i < 4; ++i) last4[i] = last[b0g + i];
    }
    float c_reg[4]  = {0.f, 0.f, 0.f, 0.f};
    float hm_reg[4] = {-FLT_MAX, -FLT_MAX, -FLT_MAX, -FLT_MAX};
    __syncthreads();

    unsigned target = 256u;
    for (int t = 0; t <= T; ++t) {
        float acc_a[4][4] = {{0,0,0,0},{0,0,0,0},{0,0,0,0},{0,0,0,0}};
        float acc_b[4][2] = {{0,0},{0,0},{0,0},{0,0}};
        float acc_c[4][2] = {{0,0},{0,0},{0,0},{0,0}};
        float4 st[4];

        // ---- stream (a): h0[t-1] -> Whh0 | Wih1 ----
        {
            const float* src = h0 + (size_t)((t + 1) & 1) * HB;
            ld_state(st, src, 0, r0, colg);
            __syncthreads();
            st_state(st, xb, r0, col);
            for (int ch = 0; ch < 16; ++ch) {
                __syncthreads();
                if (ch < 15) ld_state(st, src, (ch + 1) * 32, r0, colg);
                const float* xp = xb + (ch & 1) * 4096 + bq * 4;
                const float* wp = wa + (ch * 32) * 32 + half * 16 + jj * 4;
#pragma unroll 8
                for (int k = 0; k < 32; ++k) {
                    float4 xv = *(const float4*)(xp + k * 128);
                    float4 wv = *(const float4*)(wp + k * 32);
                    float xs[4] = {xv.x, xv.y, xv.z, xv.w};
#pragma unroll
                    for (int bb = 0; bb < 4; ++bb) {
                        acc_a[bb][0] = fmaf(xs[bb], wv.x, acc_a[bb][0]);
                        acc_a[bb][1] = fmaf(xs[bb], wv.y, acc_a[bb][1]);
                        acc_a[bb][2] = fmaf(xs[bb], wv.z, acc_a[bb][2]);
                        acc_a[bb][3] = fmaf(xs[bb], wv.w, acc_a[bb][3]);
                    }
                }
                if (ch < 15) st_state(st, xb + ((ch + 1) & 1) * 4096, r0, col);
            }
        }
        // ---- stream (b): h1[t-2] -> Whh1 (gate-pair split) ----
        {
            const float* src = h1 + (size_t)(t & 1) * HB;
            ld_state(st, src, 0, r0, colg);
            __syncthreads();
            st_state(st, xb, r0, col);
            for (int ch = 0; ch < 16; ++ch) {
                __syncthreads();
                if (ch < 15) ld_state(st, src, (ch + 1) * 32, r0, colg);
                const float* xp = xb + (ch & 1) * 4096 + bq * 4;
                const float* wp = wb + (ch * 32) * 16 + jj * 4 + half * 2;
#pragma unroll 8
                for (int k = 0; k < 32; ++k) {
                    float4 xv = *(const float4*)(xp + k * 128);
                    float2 wv = *(const float2*)(wp + k * 16);
                    float xs[4] = {xv.x, xv.y, xv.z, xv.w};
#pragma unroll
                    for (int bb = 0; bb < 4; ++bb) {
                        acc_b[bb][0] = fmaf(xs[bb], wv.x, acc_b[bb][0]);
                        acc_b[bb][1] = fmaf(xs[bb], wv.y, acc_b[bb][1]);
                    }
                }
                if (ch < 15) st_state(st, xb + ((ch + 1) & 1) * 4096, r0, col);
            }
        }
        // ---- stream (c): emb(t) -> Wih0 (gate-pair split), t < T only ----
        if (t < T) {
            const int b_l = tid & 127, kq = tid >> 7;
            const int xr = X[(size_t)(bt * 128 + b_l) * T + t];
            const float* er = emb + (size_t)xr * E;
            float4 e0, e1;
            auto ldc = [&](int kb) {
                int k0 = kb + kq * 8;
                e0 = (k0     < 100) ? *(const float4*)(er + k0)     : make_float4(0,0,0,0);
                e1 = (k0 + 4 < 100) ? *(const float4*)(er + k0 + 4) : make_float4(0,0,0,0);
            };
            auto stc = [&](float* buf) {
                int kl = kq * 8;
                buf[(kl+0)*128+b_l]=e0.x; buf[(kl+1)*128+b_l]=e0.y;
                buf[(kl+2)*128+b_l]=e0.z; buf[(kl+3)*128+b_l]=e0.w;
                buf[(kl+4)*128+b_l]=e1.x; buf[(kl+5)*128+b_l]=e1.y;
                buf[(kl+6)*128+b_l]=e1.z; buf[(kl+7)*128+b_l]=e1.w;
            };
            ldc(0);
            __syncthreads();
            stc(xb);
            for (int ch = 0; ch < 7; ++ch) {
                __syncthreads();
                if (ch < 6) ldc((ch + 1) * 16);
                const float* xp = xb + (ch & 1) * 2048 + bq * 4;
                const float* wp = wc + (ch * 16) * 16 + jj * 4 + half * 2;
#pragma unroll 8
                for (int k = 0; k < 16; ++k) {
                    float4 xv = *(const float4*)(xp + k * 128);
                    float2 wv = *(const float2*)(wp + k * 16);
                    float xs[4] = {xv.x, xv.y, xv.z, xv.w};
#pragma unroll
                    for (int bb = 0; bb < 4; ++bb) {
                        acc_c[bb][0] = fmaf(xs[bb], wv.x, acc_c[bb][0]);
                        acc_c[bb][1] = fmaf(xs[bb], wv.y, acc_c[bb][1]);
                    }
                }
                if (ch < 6) stc(xb + ((ch + 1) & 1) * 2048);
            }
        }
        // ---- gate-pair exchange + epilogue ----
        __syncthreads();
        if (half == 0) {
#pragma unroll
            for (int bb = 0; bb < 4; ++bb) {
                redS[tid2 * 8 + bb * 2 + 0] = acc_b[bb][0];
                redS[tid2 * 8 + bb * 2 + 1] = acc_b[bb][1];
            }
        } else if (t < T) {
#pragma unroll
            for (int bb = 0; bb < 4; ++bb) {
                redS[1024 + tid2 * 8 + bb * 2 + 0] = acc_c[bb][0];
                redS[1024 + tid2 * 8 + bb * 2 + 1] = acc_c[bb][1];
            }
        }
        __syncthreads();
        if (half == 0) {
            if (t < T) {        // L0(t) epilogue
                float hv[4];
#pragma unroll
                for (int bb = 0; bb < 4; ++bb) {
                    float p0 = acc_a[bb][0] + acc_c[bb][0] + bias_r[0];
                    float p1 = acc_a[bb][1] + acc_c[bb][1] + bias_r[1];
                    float p2 = acc_a[bb][2] + redS[1024 + tid2*8 + bb*2+0] + bias_r[2];
                    float p3 = acc_a[bb][3] + redS[1024 + tid2*8 + bb*2+1] + bias_r[3];
                    float ig = fsig(p0), fg = fsig(p1), gg = ftanh(p2), og = fsig(p3);
                    c_reg[bb] = fg * c_reg[bb] + ig * gg;
                    hv[bb] = og * ftanh(c_reg[bb]);
                }
                *(float4*)(h0 + (size_t)(t & 1) * HB + (size_t)jmine * B + b0g) =
                    make_float4(hv[0], hv[1], hv[2], hv[3]);
            }
        } else {
            if (t >= 1) {       // L1(t-1) epilogue
                float hv[4];
#pragma unroll
                for (int bb = 0; bb < 4; ++bb) {
                    float p0 = acc_a[bb][0] + redS[tid2*8 + bb*2+0] + bias_r[0];
                    float p1 = acc_a[bb][1] + redS[tid2*8 + bb*2+1] + bias_r[1];
                    float p2 = acc_a[bb][2] + acc_b[bb][0] + bias_r[2];
                    float p3 = acc_a[bb][3] + acc_b[bb][1] + bias_r[3];
                    float ig = fsig(p0), fg = fsig(p1), gg = ftanh(p2), og = fsig(p3);
                    c_reg[bb] = fg * c_reg[bb] + ig * gg;
                    hv[bb] = og * ftanh(c_reg[bb]);
                    if (t - 1 <= last4[bb]) hm_reg[bb] = fmaxf(hm_reg[bb], hv[bb]);
                }
                *(float4*)(h1 + (size_t)((t + 1) & 1) * HB + (size_t)jmine * B + b0g) =
                    make_float4(hv[0], hv[1], hv[2], hv[3]);
            }
        }
        // ---- grid barrier ----
        __threadfence();
        __syncthreads();
        if (tid == 0) {
            __hip_atomic_fetch_add(cnt, 1u, __ATOMIC_RELEASE, __HIP_MEMORY_SCOPE_AGENT);
            while (__hip_atomic_load(cnt, __ATOMIC_RELAXED, __HIP_MEMORY_SCOPE_AGENT) < target) {}
        }
        __syncthreads();
        __threadfence();
        target += 256u;
    }
    if (half == 1)
        *(float4*)(hmax + (size_t)jmine * B + b0g) =
            make_float4(hm_reg[0], hm_reg[1], hm_reg[2], hm_reg[3]);
}

// ---------------- final: logits[b][cls] = sum_j hmax[j][b] * Wout[cls][j] + bout ----
__global__ __launch_bounds__(64) void k_out(const float* __restrict__ hmax,
                                            const float* __restrict__ Wout,
                                            const float* __restrict__ bout,
                                            float* __restrict__ out) {
    const int b = blockIdx.x * 64 + threadIdx.x;
    float a[NC] = {0.f, 0.f, 0.f, 0.f, 0.f};
    const float* hm = hmax + b;
    for (int j = 0; j < H; ++j) {
        float hv = hm[j * B];
#pragma unroll
        for (int cls = 0; cls < NC; ++cls)
            a[cls] = fmaf(hv, Wout[cls * H + j], a[cls]);
    }
#pragma unroll
    for (int cls = 0; cls < NC; ++cls)
        out[b * NC + cls] = a[cls] + bout[cls];
}

// ---------------- launch ----------------
extern "C" void kernel_launch(void* const* d_in, const int* in_sizes, int n_in,
                              void* d_out, int out_size, void* d_ws, size_t ws_size,
                              hipStream_t stream) {
    const int*   X    = (const int*)  d_in[0];
    const float* emb  = (const float*)d_in[1];
    const float* Wih0 = (const float*)d_in[2];
    const float* Whh0 = (const float*)d_in[3];
    const float* b0   = (const float*)d_in[4];
    const float* Wih1 = (const float*)d_in[5];
    const float* Whh1 = (const float*)d_in[6];
    const float* b1   = (const float*)d_in[7];
    const float* Wout = (const float*)d_in[8];
    const float* bout = (const float*)d_in[9];
    float* out = (float*)d_out;
    float* ws  = (float*)d_ws;

    float*    hmax = ws + 4 * HB;
    int*      last = (int*)(ws + 5 * HB);
    unsigned* cnt  = (unsigned*)(ws + 5 * HB + B);

    k_init<<<(4 * HB + 255) / 256, 256, 0, stream>>>(ws, X, last, cnt);
    k_persist<<<256, 256, 146432, stream>>>(X, emb, Wih0, Whh0, b0,
                                            Wih1, Whh1, b1, ws, cnt);
    k_out<<<4, 64, 0, stream>>>(hmax, Wout, bout, out);
}

// Round 7
// 8407.989 us; speedup vs baseline: 3.1353x; 3.1353x over previous
//
#include <hip/hip_runtime.h>
#include <float.h>

#define V 50000
#define E 100
#define H 512
#define T 200
#define B 256
#define NC 5
#define HB (H * B)

// ---------------- activations (fast, ~2e-7 abs err) ----------------
__device__ __forceinline__ float fsig(float x)  { return 1.f / (1.f + __expf(-x)); }
__device__ __forceinline__ float ftanh(float x) { return 1.f - 2.f / (__expf(2.f * x) + 1.f); }

// ws: h0[2][HB] | c0[HB] | h1[2][HB] | c1[HB] | hmax[HB] | last[B]
__global__ void k_init(float* __restrict__ ws, const int* __restrict__ X,
                       int* __restrict__ last) {
    int i = blockIdx.x * 256 + threadIdx.x;
    if (i < 6 * HB)       ws[i] = 0.f;
    else if (i < 7 * HB)  ws[i] = -FLT_MAX;
    if (i < B) {
        int l = -1;
        const int* xr = X + i * T;
        for (int t = 0; t < T; ++t) if (xr[t] != V) l = t;
        last[i] = l;
    }
}

// ---------------- fused step kernel ----------------
// 1024 blocks x 256 thr. Block = (layer, jt 0..31, bt 0..15): tile 16b x 16j x 4g.
// bid = slot*8 + (jt&7): XCD-affinity (weights ~1.7 MB/XCD).
// The 4 waves of a block are 4 independent K-quarters with wave-private LDS
// staging and a register->LDS software pipeline: NO barriers in the K-loop.
// Cross-quarter reduction via LDS at the end (2 barriers total).
// Thread tile 4b x 4g at j = j0+jthr (2 B LDS per fma, conflict-free).
__global__ __launch_bounds__(256, 4) void k_step(
    int t, const int* __restrict__ X, const float* __restrict__ emb,
    const float* __restrict__ Wih0, const float* __restrict__ Whh0,
    const float* __restrict__ b0,
    const float* __restrict__ Wih1, const float* __restrict__ Whh1,
    const float* __restrict__ b1,
    float* __restrict__ ws)
{
    __shared__ float smem[8192];   // 32 KB: 4 x (xS 256 + wS 1024) + redS 3*1024

    const int tid  = threadIdx.x;
    const int lane = tid & 63;
    const int qw   = tid >> 6;     // K-quarter = wave id

    const int bid = blockIdx.x;
    const int xcd = bid & 7;
    const int s   = bid >> 3;
    const int bt  = s & 15;
    const int s2  = s >> 4;        // 0..7
    const int jt  = ((s2 & 3) << 3) | xcd;
    const int layer = s2 >> 2;

    if (layer == 0 && t >= T) return;
    if (layer == 1 && t < 1)  return;
    const int tt = t - 1;          // layer-1 time index

    float* h0   = ws;
    float* c0   = ws + 2 * HB;
    float* h1   = ws + 3 * HB;
    float* c1   = ws + 5 * HB;
    float* hmax = ws + 6 * HB;
    const int* last = (const int*)(ws + 7 * HB);

    float* xS   = smem + qw * 1280;      // [16k][16b]
    float* wS   = xS + 256;              // [16k][64c], c = jl*4+g
    float* redS = smem + 5120;           // [3][4][256]

    const int b0g  = bt * 16, j0 = jt * 16;
    const int jthr = lane & 15, bthr = lane >> 4;
    const int x_kl = lane >> 2, x_b4 = (lane & 3) * 4;   // rec-x staging
    const int e_bl = lane & 15, e_kq = lane >> 4;        // emb-x staging
    const int wrow = (lane & 3) * H + j0 + (lane >> 2);  // weight row for c=lane

    const float *srcA, *srcB, *pWA, *pWB;
    int NCH;
    if (layer == 0) {
        srcA = nullptr;
        srcB = h0 + (size_t)((t + 1) & 1) * HB;          // h0[t-1]
        pWA  = Wih0 + (size_t)wrow * E;
        pWB  = Whh0 + (size_t)wrow * H;
        NCH  = 10;   // 2 emb chunks (K=128 pad /4 quarters) + 8 rec chunks (128k)
    } else {
        srcA = h0 + (size_t)(tt & 1) * HB;               // x = h0[tt]
        srcB = h1 + (size_t)((tt + 1) & 1) * HB;         // h1[tt-1]
        pWA  = Wih1 + (size_t)wrow * H;
        pWB  = Whh1 + (size_t)wrow * H;
        NCH  = 16;   // 8 + 8 chunks of 16k
    }
    const float* erp = emb;
    if (layer == 0) erp = emb + (size_t)X[(b0g + e_bl) * T + t] * E;

    float4 rx, rw[4];
    bool emb_reg = false;

    auto ld = [&](int ch) {                    // global -> regs (prefetch)
        if (layer == 0 && ch < 2) {            // embedding chunk, zero-padded
            const int kb = qw * 32 + ch * 16;
            const int k  = kb + e_kq * 4;
            rx = (k < E) ? *(const float4*)(erp + k) : make_float4(0.f,0.f,0.f,0.f);
#pragma unroll
            for (int u = 0; u < 4; ++u) {
                int kk = kb + u * 4;
                rw[u] = (kk < E) ? *(const float4*)(pWA + kk) : make_float4(0.f,0.f,0.f,0.f);
            }
            emb_reg = true;
        } else {
            const float* sp; const float* wpp; int kb;
            if (layer == 0)   { kb = qw*128 + (ch-2)*16; sp = srcB; wpp = pWB; }
            else if (ch < 8)  { kb = qw*128 + ch*16;     sp = srcA; wpp = pWA; }
            else              { kb = qw*128 + (ch-8)*16; sp = srcB; wpp = pWB; }
            rx = *(const float4*)(sp + (size_t)(kb + x_kl) * B + b0g + x_b4);
#pragma unroll
            for (int u = 0; u < 4; ++u)
                rw[u] = *(const float4*)(wpp + kb + u * 4);
            emb_reg = false;
        }
    };
    auto st = [&]() {                          // regs -> wave-private LDS
        if (emb_reg) {
            const int kl0 = e_kq * 4;
            xS[(kl0+0)*16 + e_bl] = rx.x;
            xS[(kl0+1)*16 + e_bl] = rx.y;
            xS[(kl0+2)*16 + e_bl] = rx.z;
            xS[(kl0+3)*16 + e_bl] = rx.w;
        } else {
            *(float4*)(xS + x_kl * 16 + x_b4) = rx;
        }
#pragma unroll
        for (int u = 0; u < 4; ++u) {          // transpose: 16 scalar ds_writes
            wS[(u*4+0)*64 + lane] = rw[u].x;
            wS[(u*4+1)*64 + lane] = rw[u].y;
            wS[(u*4+2)*64 + lane] = rw[u].z;
            wS[(u*4+3)*64 + lane] = rw[u].w;
        }
    };

    float acc[4][4] = {{0,0,0,0},{0,0,0,0},{0,0,0,0},{0,0,0,0}};
    const float* xp = xS + bthr * 4;
    const float* wp = wS + jthr * 4;

    ld(0);
    for (int ch = 0; ch < NCH; ++ch) {
        st();                                  // consumes regs of chunk ch
        if (ch + 1 < NCH) ld(ch + 1);          // globals in flight during fma
#pragma unroll
        for (int k = 0; k < 16; ++k) {
            float4 xv = *(const float4*)(xp + k * 16);   // 4 uniq, 16-lane bcast
            float4 wv = *(const float4*)(wp + k * 64);   // 16 uniq, 2-way
            float xs[4] = {xv.x, xv.y, xv.z, xv.w};
#pragma unroll
            for (int bb = 0; bb < 4; ++bb) {
                acc[bb][0] = fmaf(xs[bb], wv.x, acc[bb][0]);
                acc[bb][1] = fmaf(xs[bb], wv.y, acc[bb][1]);
                acc[bb][2] = fmaf(xs[bb], wv.z, acc[bb][2]);
                acc[bb][3] = fmaf(xs[bb], wv.w, acc[bb][3]);
            }
        }
    }

    // ---- cross-quarter reduction + epilogue ----
    __syncthreads();
    if (qw > 0) {
#pragma unroll
        for (int bb = 0; bb < 4; ++bb)
            *(float4*)(redS + (qw-1)*1024 + bb*256 + lane*4) =
                make_float4(acc[bb][0], acc[bb][1], acc[bb][2], acc[bb][3]);
    }
    __syncthreads();
    if (qw == 0) {
        const int j   = j0 + jthr;
        const int bb0 = b0g + bthr * 4;
        float* cst  = layer ? c1 : c0;
        float* hout = layer ? (h1 + (size_t)(tt & 1) * HB)
                            : (h0 + (size_t)(t  & 1) * HB);
        const float* bias = layer ? b1 : b0;
        const float bi = bias[0*H+j], bf = bias[1*H+j];
        const float bg = bias[2*H+j], bo = bias[3*H+j];

        float4 cp = *(const float4*)(cst + (size_t)j * B + bb0);
        float cpa[4] = {cp.x, cp.y, cp.z, cp.w};
        float cn[4], hn[4];
#pragma unroll
        for (int bb = 0; bb < 4; ++bb) {
            float g0 = acc[bb][0], g1 = acc[bb][1], g2 = acc[bb][2], g3 = acc[bb][3];
#pragma unroll
            for (int q = 0; q < 3; ++q) {
                float4 o = *(const float4*)(redS + q*1024 + bb*256 + lane*4);
                g0 += o.x; g1 += o.y; g2 += o.z; g3 += o.w;
            }
            float ig = fsig(g0 + bi), fg = fsig(g1 + bf);
            float gg = ftanh(g2 + bg), og = fsig(g3 + bo);
            cn[bb] = fg * cpa[bb] + ig * gg;
            hn[bb] = og * ftanh(cn[bb]);
        }
        *(float4*)(cst  + (size_t)j * B + bb0) = make_float4(cn[0],cn[1],cn[2],cn[3]);
        *(float4*)(hout + (size_t)j * B + bb0) = make_float4(hn[0],hn[1],hn[2],hn[3]);
        if (layer == 1) {
            float4 hm = *(const float4*)(hmax + (size_t)j * B + bb0);
            float hma[4] = {hm.x, hm.y, hm.z, hm.w};
#pragma unroll
            for (int bb = 0; bb < 4; ++bb)
                if (tt <= last[bb0 + bb]) hma[bb] = fmaxf(hma[bb], hn[bb]);
            *(float4*)(hmax + (size_t)j * B + bb0) =
                make_float4(hma[0], hma[1], hma[2], hma[3]);
        }
    }
}

// ---------------- final: logits[b][cls] = sum_j hmax[j][b] * Wout[cls][j] + bout ----
__global__ __launch_bounds__(64) void k_out(const float* __restrict__ hmax,
                                            const float* __restrict__ Wout,
                                            const float* __restrict__ bout,
                                            float* __restrict__ out) {
    const int b = blockIdx.x * 64 + threadIdx.x;
    float a[NC] = {0.f, 0.f, 0.f, 0.f, 0.f};
    const float* hm = hmax + b;
    for (int j = 0; j < H; ++j) {
        float hv = hm[j * B];
#pragma unroll
        for (int cls = 0; cls < NC; ++cls)
            a[cls] = fmaf(hv, Wout[cls * H + j], a[cls]);
    }
#pragma unroll
    for (int cls = 0; cls < NC; ++cls)
        out[b * NC + cls] = a[cls] + bout[cls];
}

// ---------------- launch ----------------
extern "C" void kernel_launch(void* const* d_in, const int* in_sizes, int n_in,
                              void* d_out, int out_size, void* d_ws, size_t ws_size,
                              hipStream_t stream) {
    const int*   X    = (const int*)  d_in[0];
    const float* emb  = (const float*)d_in[1];
    const float* Wih0 = (const float*)d_in[2];
    const float* Whh0 = (const float*)d_in[3];
    const float* b0   = (const float*)d_in[4];
    const float* Wih1 = (const float*)d_in[5];
    const float* Whh1 = (const float*)d_in[6];
    const float* b1   = (const float*)d_in[7];
    const float* Wout = (const float*)d_in[8];
    const float* bout = (const float*)d_in[9];
    float* out = (float*)d_out;
    float* ws  = (float*)d_ws;

    float* hmax = ws + 6 * HB;
    int*   last = (int*)(ws + 7 * HB);

    k_init<<<(7 * HB + 255) / 256, 256, 0, stream>>>(ws, X, last);

    // Dispatch t computes layer0(t) and layer1(t-1); t = 0..T inclusive.
    for (int t = 0; t <= T; ++t) {
        k_step<<<1024, 256, 0, stream>>>(t, X, emb, Wih0, Whh0, b0,
                                         Wih1, Whh1, b1, ws);
    }

    k_out<<<4, 64, 0, stream>>>(hmax, Wout, bout, out);
}

// Round 8
// 4897.924 us; speedup vs baseline: 5.3822x; 1.7166x over previous
//
#include <hip/hip_runtime.h>
#include <float.h>

#define V 50000
#define E 100
#define H 512
#define T 200
#define B 256
#define NC 5
#define K0 640            // layer0 concat-K: 128 (emb pad) + 512
#define K1 1024           // layer1 concat-K: 512 + 512
#define NH (B * H)        // 131072
#define NW0 (2048 * K0)
#define NW1 (2048 * K1)
#define LOSC 4096.0f      // lo-plane scale (2^12) keeps lo out of fp16 denormals
#define ILOSC (1.0f / 4096.0f)

typedef _Float16 half8 __attribute__((ext_vector_type(8)));
typedef float floatx4 __attribute__((ext_vector_type(4)));

// ---------------- activations ----------------
__device__ __forceinline__ float fsig(float x)  { return 1.f / (1.f + __expf(-x)); }
__device__ __forceinline__ float ftanh(float x) { return 1.f - 2.f / (__expf(2.f * x) + 1.f); }

// ---------------- workspace map ----------------
struct WS {
    _Float16 *W0h, *W0l, *W1h, *W1l;   // [2048][K] split planes, c = j*4+g
    _Float16 *h0h, *h0l, *h1h, *h1l;   // [2 slots][B][H] split planes (lo pre-scaled)
    float *c0, *c1, *hmax;             // [B][H]
    int *last;
};
__device__ __host__ inline WS wsmap(char* p) {
    WS w;
    w.W0h = (_Float16*)p;  p += (size_t)NW0 * 2;
    w.W0l = (_Float16*)p;  p += (size_t)NW0 * 2;
    w.W1h = (_Float16*)p;  p += (size_t)NW1 * 2;
    w.W1l = (_Float16*)p;  p += (size_t)NW1 * 2;
    w.h0h = (_Float16*)p;  p += (size_t)2 * NH * 2;
    w.h0l = (_Float16*)p;  p += (size_t)2 * NH * 2;
    w.h1h = (_Float16*)p;  p += (size_t)2 * NH * 2;
    w.h1l = (_Float16*)p;  p += (size_t)2 * NH * 2;
    w.c0   = (float*)p;    p += (size_t)NH * 4;
    w.c1   = (float*)p;    p += (size_t)NH * 4;
    w.hmax = (float*)p;    p += (size_t)NH * 4;
    w.last = (int*)p;
    return w;
}

// ---------------- prep: split weights into fp16 hi/lo catenated layout ----------------
__global__ void k_prep(const float* __restrict__ Wih0, const float* __restrict__ Whh0,
                       const float* __restrict__ Wih1, const float* __restrict__ Whh1,
                       char* wsraw) {
    WS w = wsmap(wsraw);
    int idx = blockIdx.x * 256 + threadIdx.x;
    if (idx < NW0) {
        int c = idx / K0, k = idx - c * K0;
        int jx = c >> 2, g = c & 3, row = g * H + jx;
        float v = 0.f;
        if (k < 128) { if (k < E) v = Wih0[(size_t)row * E + k]; }
        else           v = Whh0[(size_t)row * H + (k - 128)];
        _Float16 hh = (_Float16)v;
        w.W0h[idx] = hh;
        w.W0l[idx] = (_Float16)((v - (float)hh) * LOSC);
    } else if (idx < NW0 + NW1) {
        int i2 = idx - NW0;
        int c = i2 / K1, k = i2 - c * K1;
        int jx = c >> 2, g = c & 3, row = g * H + jx;
        float v = (k < H) ? Wih1[(size_t)row * H + k]
                          : Whh1[(size_t)row * H + (k - H)];
        _Float16 hh = (_Float16)v;
        w.W1h[i2] = hh;
        w.W1l[i2] = (_Float16)((v - (float)hh) * LOSC);
    }
}

// ---------------- init: zero states, hmax=-FLT_MAX, last[b] ----------------
__global__ void k_init(const int* __restrict__ X, char* wsraw) {
    WS w = wsmap(wsraw);
    int i = blockIdx.x * 256 + threadIdx.x;
    if (i < 524288)                     ((unsigned*)w.h0h)[i] = 0u;        // all h planes
    else if (i < 524288 + 262144)       ((unsigned*)w.c0)[i - 524288] = 0u; // c0,c1
    else if (i < 524288 + 262144 + NH)  w.hmax[i - 786432] = -FLT_MAX;
    if (i < B) {
        int l = -1;
        const int* xr = X + i * T;
        for (int t = 0; t < T; ++t) if (xr[t] != V) l = t;
        w.last[i] = l;
    }
}

// ---------------- K-quarter MFMA loop (per wave), all frags direct from global/L2 ----
template <int LAYER>
__device__ __forceinline__ void run_mm(
    int t, const int* __restrict__ X, const float* __restrict__ emb,
    const _Float16* __restrict__ Wh, const _Float16* __restrict__ Wl,
    const _Float16* __restrict__ xh0, const _Float16* __restrict__ xl0,
    const _Float16* __restrict__ xh1, const _Float16* __restrict__ xl1,
    int c0g, int b0gl, int m, int qq, int wq,
    floatx4 (&acc0)[16], floatx4 (&acc1)[16])
{
    const int KT  = LAYER ? K1 : K0;
    const int NKB = LAYER ? 8 : 5;    // k-blocks of 32 per wave (kb = wq + 4*i)
    int erow[4];
    if (LAYER == 0) {
#pragma unroll
        for (int bs = 0; bs < 4; ++bs)
            erow[bs] = X[(b0gl + bs * 16 + m) * T + t];
    }
    half8 A_h[2][4], A_l[2][4], B_h[2][4], B_l[2][4];

    auto ldkb = [&](int kb, int buf) {
        const int ko = kb * 32 + qq * 8;
#pragma unroll
        for (int cs = 0; cs < 4; ++cs) {
            const size_t ro = (size_t)(c0g + cs * 16 + m) * KT + ko;
            A_h[buf][cs] = *(const half8*)(Wh + ro);
            A_l[buf][cs] = *(const half8*)(Wl + ro);
        }
        if (LAYER == 0 && kb < 4) {            // embedding part, convert on the fly
#pragma unroll
            for (int bs = 0; bs < 4; ++bs) {
                const float* er = emb + (size_t)erow[bs] * E;
                float4 fa = make_float4(0.f,0.f,0.f,0.f), fb = fa;
                if (ko <= 96) fa = *(const float4*)(er + ko);
                if (ko <= 92) fb = *(const float4*)(er + ko + 4);
                float e[8] = {fa.x,fa.y,fa.z,fa.w, fb.x,fb.y,fb.z,fb.w};
                half8 hh, hl;
#pragma unroll
                for (int u = 0; u < 8; ++u) {
                    _Float16 hv = (_Float16)e[u];
                    hh[u] = hv;
                    hl[u] = (_Float16)((e[u] - (float)hv) * LOSC);
                }
                B_h[buf][bs] = hh; B_l[buf][bs] = hl;
            }
        } else {
            const _Float16 *sh, *sl; int kk;
            if (LAYER == 0)      { sh = xh0; sl = xl0; kk = ko - 128; }
            else if (kb < 16)    { sh = xh0; sl = xl0; kk = ko; }
            else                 { sh = xh1; sl = xl1; kk = ko - 512; }
#pragma unroll
            for (int bs = 0; bs < 4; ++bs) {
                const size_t ro = (size_t)(b0gl + bs * 16 + m) * H + kk;
                B_h[buf][bs] = *(const half8*)(sh + ro);
                B_l[buf][bs] = *(const half8*)(sl + ro);
            }
        }
    };

    ldkb(wq, 0);
#pragma unroll
    for (int i = 0; i < NKB; ++i) {
        const int cur = i & 1;
        if (i + 1 < NKB) ldkb(wq + 4 * (i + 1), cur ^ 1);   // prefetch next k-block
#pragma unroll
        for (int cs = 0; cs < 4; ++cs)
#pragma unroll
            for (int bs = 0; bs < 4; ++bs) {
                const int ti = cs * 4 + bs;
                acc0[ti] = __builtin_amdgcn_mfma_f32_16x16x32_f16(A_h[cur][cs], B_h[cur][bs], acc0[ti], 0, 0, 0);
                acc1[ti] = __builtin_amdgcn_mfma_f32_16x16x32_f16(A_h[cur][cs], B_l[cur][bs], acc1[ti], 0, 0, 0);
                acc1[ti] = __builtin_amdgcn_mfma_f32_16x16x32_f16(A_l[cur][cs], B_h[cur][bs], acc1[ti], 0, 0, 0);
            }
    }
}

// ---------------- fused step: 256 blocks, block = (layer, cblk, bblk), 4 k-quarter waves ----
// bid = ((layer*4 + bblk)*4 + chi)*8 + xcd, cblk = chi*8+xcd -> weights XCD-pinned (~1.7 MB/XCD)
__global__ __launch_bounds__(256, 1) void k_step(
    int t, const int* __restrict__ X, const float* __restrict__ emb,
    const float* __restrict__ b0, const float* __restrict__ b1,
    char* __restrict__ wsraw)
{
    extern __shared__ float red[];    // [4 waves][64 b][68]  (c-minor, +4 pad)

    const int tid = threadIdx.x, lane = tid & 63, wq = tid >> 6;
    const int m = lane & 15, qq = lane >> 4;
    const int bid = blockIdx.x;
    const int xcd = bid & 7, slot = bid >> 3;
    const int layer = slot >> 4, bblk = (slot >> 2) & 3, chi = slot & 3;
    const int cblk = chi * 8 + xcd;
    if (layer == 0 && t >= T) return;
    if (layer == 1 && t < 1)  return;
    const int tt = t - 1;
    const int c0g = cblk * 64, b0gl = bblk * 64, j0g = cblk * 16;

    WS w = wsmap(wsraw);

    floatx4 acc0[16], acc1[16];
#pragma unroll
    for (int i = 0; i < 16; ++i) {
        floatx4 z = {0.f, 0.f, 0.f, 0.f};
        acc0[i] = z; acc1[i] = z;
    }

    if (layer == 0)
        run_mm<0>(t, X, emb, w.W0h, w.W0l,
                  w.h0h + (size_t)((t + 1) & 1) * NH, w.h0l + (size_t)((t + 1) & 1) * NH,
                  nullptr, nullptr, c0g, b0gl, m, qq, wq, acc0, acc1);
    else
        run_mm<1>(tt, X, emb, w.W1h, w.W1l,
                  w.h0h + (size_t)(tt & 1) * NH, w.h0l + (size_t)(tt & 1) * NH,
                  w.h1h + (size_t)((tt + 1) & 1) * NH, w.h1l + (size_t)((tt + 1) & 1) * NH,
                  c0g, b0gl, m, qq, wq, acc0, acc1);

    // ---- fold lo-acc, dump k-quarter partials ----
#pragma unroll
    for (int cs = 0; cs < 4; ++cs)
#pragma unroll
        for (int bs = 0; bs < 4; ++bs) {
            floatx4 v = acc0[cs * 4 + bs] + acc1[cs * 4 + bs] * ILOSC;
            const int bl = bs * 16 + m, cl = cs * 16 + qq * 4;
            *(floatx4*)&red[((wq * 64 + bl) * 68 + cl)] = v;
        }
    __syncthreads();

    // ---- reduce 4 quarters + epilogue; wave wq owns b-strip [wq*16, wq*16+16) ----
    const int jj = lane & 15, bq = lane >> 4;
    const int j = j0g + jj;
    const float* bias = layer ? b1 : b0;
    const float bv0 = bias[0 * H + j], bv1 = bias[1 * H + j];
    const float bv2 = bias[2 * H + j], bv3 = bias[3 * H + j];
    float* cst = layer ? w.c1 : w.c0;
    _Float16* oh = layer ? (w.h1h + (size_t)(tt & 1) * NH) : (w.h0h + (size_t)(t & 1) * NH);
    _Float16* ol = layer ? (w.h1l + (size_t)(tt & 1) * NH) : (w.h0l + (size_t)(t & 1) * NH);

#pragma unroll
    for (int bi = 0; bi < 4; ++bi) {
        const int bl = wq * 16 + bq + 4 * bi;     // 16 lanes (jj) share this b
        const int bg = b0gl + bl;
        floatx4 g = *(floatx4*)&red[((0 * 64 + bl) * 68 + jj * 4)];
#pragma unroll
        for (int q2 = 1; q2 < 4; ++q2)
            g += *(floatx4*)&red[((q2 * 64 + bl) * 68 + jj * 4)];
        float ig = fsig (g.x + bv0);
        float fg = fsig (g.y + bv1);
        float gg = ftanh(g.z + bv2);
        float og = fsig (g.w + bv3);
        float cold = cst[(size_t)bg * H + j];
        float cn = fg * cold + ig * gg;
        float hn = og * ftanh(cn);
        cst[(size_t)bg * H + j] = cn;
        _Float16 hh = (_Float16)hn;
        oh[(size_t)bg * H + j] = hh;
        ol[(size_t)bg * H + j] = (_Float16)((hn - (float)hh) * LOSC);
        if (layer == 1 && tt <= w.last[bg]) {
            float* hp = w.hmax + (size_t)bg * H + j;
            *hp = fmaxf(*hp, hn);
        }
    }
}

// ---------------- final: logits[b][cls] = sum_j hmax[b][j] * Wout[cls][j] + bout ----
__global__ __launch_bounds__(64) void k_out(const float* __restrict__ hmax,
                                            const float* __restrict__ Wout,
                                            const float* __restrict__ bout,
                                            float* __restrict__ out) {
    const int b = blockIdx.x * 64 + threadIdx.x;
    float a[NC] = {0.f, 0.f, 0.f, 0.f, 0.f};
    const float* hm = hmax + (size_t)b * H;
    for (int j = 0; j < H; ++j) {
        float hv = hm[j];
#pragma unroll
        for (int cls = 0; cls < NC; ++cls)
            a[cls] = fmaf(hv, Wout[cls * H + j], a[cls]);
    }
#pragma unroll
    for (int cls = 0; cls < NC; ++cls)
        out[b * NC + cls] = a[cls] + bout[cls];
}

// ---------------- launch ----------------
extern "C" void kernel_launch(void* const* d_in, const int* in_sizes, int n_in,
                              void* d_out, int out_size, void* d_ws, size_t ws_size,
                              hipStream_t stream) {
    const int*   X    = (const int*)  d_in[0];
    const float* emb  = (const float*)d_in[1];
    const float* Wih0 = (const float*)d_in[2];
    const float* Whh0 = (const float*)d_in[3];
    const float* b0   = (const float*)d_in[4];
    const float* Wih1 = (const float*)d_in[5];
    const float* Whh1 = (const float*)d_in[6];
    const float* b1   = (const float*)d_in[7];
    const float* Wout = (const float*)d_in[8];
    const float* bout = (const float*)d_in[9];
    float* out = (float*)d_out;
    char* ws = (char*)d_ws;
    WS w = wsmap(ws);

    k_prep<<<(NW0 + NW1 + 255) / 256, 256, 0, stream>>>(Wih0, Whh0, Wih1, Whh1, ws);
    k_init<<<(524288 + 262144 + NH + 255) / 256, 256, 0, stream>>>(X, ws);

    // Dispatch t computes layer0(t) and layer1(t-1); t = 0..T inclusive.
    for (int t = 0; t <= T; ++t) {
        k_step<<<256, 256, 4 * 64 * 68 * sizeof(float), stream>>>(t, X, emb, b0, b1, ws);
    }

    k_out<<<4, 64, 0, stream>>>(w.hmax, Wout, bout, out);
}